// Round 11
// baseline (151.040 us; speedup 1.0000x reference)
//
#include <hip/hip_runtime.h>

#define B_   8
#define N_   512
#define IND  256
#define H_   4
#define PH   32
#define OD   128   // H_*PH
#define TI   4     // targets per block (attn)

typedef float v2f __attribute__((ext_vector_type(2)));

// leaky 0.4 * log2(e), and 0.6 * log2(e): logits in log2 domain -> v_exp_f32.
#define ATT_SCALE 0.5770780163555854f
#define DLR_SCALE 0.8656170245333781f

template <int PAT>
__device__ __forceinline__ float dpp_add(float x) {
    int yi = __builtin_amdgcn_mov_dpp(__float_as_int(x), PAT, 0xF, 0xF, true);
    return x + __int_as_float(yi);
}

__device__ __forceinline__ float fast_exp2(float x) {
#if __has_builtin(__builtin_amdgcn_exp2f)
    return __builtin_amdgcn_exp2f(x);
#else
    return exp2f(x);
#endif
}

// Packed fp32 FMA: d += a*b on both halves, ONE VOP3P instruction.
// (r8: fp32 VOP3P is 2-pass on the SIMD -- saves fetch/decode, not issue.)
__device__ __forceinline__ void pk_fma(v2f& d, v2f a, v2f b) {
    asm("v_pk_fma_f32 %0, %1, %2, %0" : "+v"(d) : "v"(a), "v"(b));
}

// Packed fp32 FMA with src0 broadcast via op_sel (HI selects a.x or a.y).
template <int HI>
__device__ __forceinline__ void pk_fma_bc(v2f& d, v2f a, v2f b) {
    if constexpr (HI == 0)
        asm("v_pk_fma_f32 %0, %1, %2, %0 op_sel:[0,0,0] op_sel_hi:[0,1,1]"
            : "+v"(d) : "v"(a), "v"(b));
    else
        asm("v_pk_fma_f32 %0, %1, %2, %0 op_sel:[1,0,0] op_sel_hi:[1,1,1]"
            : "+v"(d) : "v"(a), "v"(b));
}

// Packed fp32 add: one VOP3P instruction for two adds.
__device__ __forceinline__ v2f pk_add(v2f a, v2f b) {
    v2f d;
    asm("v_pk_add_f32 %0, %1, %2" : "=v"(d) : "v"(a), "v"(b));
    return d;
}

// ---------------------------------------------------------------------------
// Kernel 1 v12: projections. r10 DIAGNOSIS: warm proj = ~3us (rep-1 of the
// doubled body was nearly free); the ~30us of rep-0 is cold-miss latency in
// the shadow of the 268MB poison-fill writeback. Structure is NOT the cost;
// MLP is the only kernel-side lever against a latency shadow. v12 = r10 core
// with the W prefetch ring deepened 2 -> 4 buffers (4 chunk-pairs in flight
// per thread; static indices via #pragma unroll 4). VGPR ~91 < 128 (512,2).
// Everything else proven: 8 rows/block, 512 thr = og32 x ks8 x which2,
// W read once per block, stride-33 LDS combine, pk_fma_bc main loop.
// ---------------------------------------------------------------------------
__global__ __launch_bounds__(512, 2) void proj_kernel(
    const float* __restrict__ x,
    const float* __restrict__ Wl, const float* __restrict__ bl,
    const float* __restrict__ Wr, const float* __restrict__ br,
    const float* __restrict__ att,
    float* __restrict__ xl, float* __restrict__ xr,
    float* __restrict__ dl, float* __restrict__ dr)
{
    __shared__ float xs[8 * IND];        // 8 KB
    __shared__ float comb[8][64][33];    // 67.6 KB

    const int t = threadIdx.x;
    const int row0 = blockIdx.x * 8;

    ((float4*)xs)[t] = ((const float4*)(x + (size_t)row0 * IND))[t];
    __syncthreads();

    const int og    = t & 31;        // col quad: cols og*4 .. og*4+3
    const int ks    = (t >> 5) & 7;  // K slice: k0 = ks*32
    const int which = t >> 8;        // 0: Wl->xl/dl, 1: Wr->xr/dr
    const int o0 = og * 4;
    const int k0 = ks * 32;
    const float* W = (which ? Wr : Wl) + (size_t)k0 * OD + o0;

    v2f acc2[8][2];
    #pragma unroll
    for (int r = 0; r < 8; ++r) {
        acc2[r][0] = (v2f){0.f, 0.f};
        acc2[r][1] = (v2f){0.f, 0.f};
    }

    // 4-deep W ring: chunks 0..2 in flight before the loop, 4 in steady state
    float4 wb[4][2];
    #pragma unroll
    for (int i = 0; i < 3; ++i) {
        wb[i][0] = *(const float4*)(W + (size_t)(2 * i) * OD);
        wb[i][1] = *(const float4*)(W + (size_t)(2 * i + 1) * OD);
    }

    #pragma unroll 4
    for (int s = 0; s < 16; ++s) {       // 16 chunks of 2 k (K=32 per thread)
        if (s + 3 < 16) {
            const float* Wq = W + (size_t)(2 * (s + 3)) * OD;
            wb[(s + 3) & 3][0] = *(const float4*)(Wq);
            wb[(s + 3) & 3][1] = *(const float4*)(Wq + OD);
        }
        const int cur = s & 3;
        v2f w0lo = (v2f){wb[cur][0].x, wb[cur][0].y};
        v2f w0hi = (v2f){wb[cur][0].z, wb[cur][0].w};
        v2f w1lo = (v2f){wb[cur][1].x, wb[cur][1].y};
        v2f w1hi = (v2f){wb[cur][1].z, wb[cur][1].w};
        #pragma unroll
        for (int r = 0; r < 8; ++r) {
            float2 xv = *(const float2*)(&xs[r * IND + k0 + 2 * s]);
            v2f xp = (v2f){xv.x, xv.y};
            pk_fma_bc<0>(acc2[r][0], xp, w0lo);  // k0 x cols 0,1
            pk_fma_bc<0>(acc2[r][1], xp, w0hi);  // k0 x cols 2,3
            pk_fma_bc<1>(acc2[r][0], xp, w1lo);  // k1 x cols 0,1
            pk_fma_bc<1>(acc2[r][1], xp, w1hi);  // k1 x cols 2,3
        }
    }

    // stage all 8 K-slice partials; banks (33*pid+i)%32 -> conflict-free
    const int pid = og | (which << 5);   // 0..63
    #pragma unroll
    for (int r = 0; r < 8; ++r) {
        comb[ks][pid][r * 4 + 0] = acc2[r][0].x;
        comb[ks][pid][r * 4 + 1] = acc2[r][0].y;
        comb[ks][pid][r * 4 + 2] = acc2[r][1].x;
        comb[ks][pid][r * 4 + 3] = acc2[r][1].y;
    }
    __syncthreads();

    // final: remap thread -> (which', row', og'); one float4 output each
    const int ogf = t & 31;
    const int rf  = (t >> 5) & 7;
    const int whf = t >> 8;
    const int pidf = ogf | (whf << 5);
    const float* bb = whf ? br : bl;
    float* dst = whf ? xr : xl;
    float* dp  = whf ? dr : dl;
    float4 bv = *(const float4*)(bb + ogf * 4);
    float4 av = *(const float4*)(att + ogf * 4);
    const float bvf[4] = {bv.x, bv.y, bv.z, bv.w};
    const float avf[4] = {av.x, av.y, av.z, av.w};
    float y[4];
    #pragma unroll
    for (int c = 0; c < 4; ++c) {
        const int idx = rf * 4 + c;
        float s01 = comb[0][pidf][idx] + comb[1][pidf][idx];
        float s23 = comb[2][pidf][idx] + comb[3][pidf][idx];
        float s45 = comb[4][pidf][idx] + comb[5][pidf][idx];
        float s67 = comb[6][pidf][idx] + comb[7][pidf][idx];
        y[c] = ((s01 + s23) + (s45 + s67)) + bvf[c];
    }
    *(float4*)(&dst[(size_t)(row0 + rf) * OD + ogf * 4]) =
        make_float4(y[0], y[1], y[2], y[3]);
    // rank-1 part: dl/dr[n,h] = 0.6*log2e * sum_c att[h,c]*y[c]
    float dc = fmaf(avf[0], y[0], fmaf(avf[1], y[1],
               fmaf(avf[2], y[2], avf[3] * y[3])));
    dc += __shfl_xor(dc, 1);
    dc += __shfl_xor(dc, 2);
    dc += __shfl_xor(dc, 4);   // sums the 8 og-lanes of one head
    if ((ogf & 7) == 0)
        dp[(size_t)(row0 + rf) * H_ + (ogf >> 3)] = DLR_SCALE * dc;
}

// ---------------------------------------------------------------------------
// Kernel 2 v10: masked-softmax attention, LDS-STAGED operands.
// r7-r9 theory update: three VALU cuts were null because attn is co-bound by
// VMEM line processing -- per u each wave issued ~64 line-requests (2 xl
// float4 gathers = 32, adj int4 gather = 16, dl gather = 16). v10 cuts that
// ~3x: the 32-row xl strip (16 KB/u) is cooperatively staged into LDS with
// FULLY COALESCED float4 loads (8 lines/wave/load); adj+dl staged by one
// wave (int4/float4, 32+8 requests per block per u). T14 split per u:
// {issue loads u+1} -> {compute u from LDS} -> {write u+1} -> barrier (1/u,
// double-buffered). Register-neutral: staging regs replace the old
// va/vb/mj/dj pipeline regs -> VGPR stays ~64 at (512,4).
// xls rows padded to 129 floats: read banks (js+8cq+e)%32 = 2-way, free.
// LDS unioned: main {xls 33KB + adjs/dls 2KB} / epilogue {sacc+ssum 35.8KB}.
// Inner e2/exp2/PV math byte-identical to v8 (proven numerics).
// ---------------------------------------------------------------------------
__global__ __launch_bounds__(512, 4) void attn_kernel(
    const int* __restrict__ adj, const float* __restrict__ att,
    const float* __restrict__ bias,
    const float* __restrict__ xl, const float* __restrict__ xr,
    const float* __restrict__ dl, const float* __restrict__ dr,
    float* __restrict__ out)
{
    __shared__ __attribute__((aligned(16))) char lds_raw[36864];
    float (*xls)[32][129] = (float (*)[32][129])(lds_raw);        // 2x16.5KB
    int4  (*adjs)[32]     = (int4  (*)[32])(lds_raw + 33024);     // 2x512B
    float (*dls)[32][4]   = (float (*)[32][4])(lds_raw + 34048);  // 2x512B

    const int t = threadIdx.x;
    const int bid = (blockIdx.x & 7) * 128 + (blockIdx.x >> 3);
    const int b  = bid >> 7;
    const int i0 = (bid & 127) * TI;
    const int cq = t & 3;
    const int js = (t >> 2) & 31;   // 32 j-slices
    const int h  = t >> 7;
    const int cbase = h * PH + cq * 8;

    // preload att (pre-scaled by 0.4*log2e) and xr pair-fragments (v2f)
    float atS[8];
    {
        const float* ap = att + cbase;
        float4 a0 = *(const float4*)(ap);
        float4 a1 = *(const float4*)(ap + 4);
        atS[0] = ATT_SCALE * a0.x; atS[1] = ATT_SCALE * a0.y;
        atS[2] = ATT_SCALE * a0.z; atS[3] = ATT_SCALE * a0.w;
        atS[4] = ATT_SCALE * a1.x; atS[5] = ATT_SCALE * a1.y;
        atS[6] = ATT_SCALE * a1.z; atS[7] = ATT_SCALE * a1.w;
    }
    v2f xrv[TI][4];
    #pragma unroll
    for (int il = 0; il < TI; ++il) {
        const float* xp = xr + ((size_t)(b * N_ + i0 + il)) * OD + cbase;
        float4 r0 = *(const float4*)(xp);
        float4 r1 = *(const float4*)(xp + 4);
        xrv[il][0] = (v2f){r0.x, r0.y};
        xrv[il][1] = (v2f){r0.z, r0.w};
        xrv[il][2] = (v2f){r1.x, r1.y};
        xrv[il][3] = (v2f){r1.z, r1.w};
    }

    v2f acc[TI][4];
    float sumw[TI];
    #pragma unroll
    for (int il = 0; il < TI; ++il) {
        sumw[il] = 0.f;
        #pragma unroll
        for (int m = 0; m < 4; ++m) acc[il][m] = (v2f){0.f, 0.f};
    }

    // staging geometry: thread t covers float4s f = t (rows 0..15) and
    // f = t+512 (rows 16..31) of each 32-row strip; fully coalesced.
    const int fr0 = t >> 5;            // 0..15
    const int fs  = (t & 31) * 4;      // float offset of the float4 in a row
    const float* xlbase = xl + (size_t)(b * N_) * OD;
    const int*   ajbase = adj + (size_t)(b * N_) * N_ + i0;
    const float* dlbase = dl + (size_t)(b * N_) * H_;

    // ---- prologue: stage strip 0 ----
    {
        float4 x0 = *(const float4*)(xlbase + (size_t)fr0 * OD + fs);
        float4 x1 = *(const float4*)(xlbase + (size_t)(fr0 + 16) * OD + fs);
        int4 a = {0, 0, 0, 0}; float4 d = {0.f, 0.f, 0.f, 0.f};
        if (t < 32) {
            a = *(const int4*)(ajbase + (size_t)t * N_);
            d = *(const float4*)(dlbase + t * H_);
        }
        float* w0 = &xls[0][fr0][fs];
        w0[0] = x0.x; w0[1] = x0.y; w0[2] = x0.z; w0[3] = x0.w;
        float* w1 = &xls[0][fr0 + 16][fs];
        w1[0] = x1.x; w1[1] = x1.y; w1[2] = x1.z; w1[3] = x1.w;
        if (t < 32) { adjs[0][t] = a; *(float4*)dls[0][t] = d; }
    }
    __syncthreads();

    #pragma unroll 2
    for (int u = 0; u < 16; ++u) {
        const int cur = u & 1, nxt = cur ^ 1;

        // T14 issue-early: strip u+1 global loads (hide under compute)
        float4 x0 = {0.f, 0.f, 0.f, 0.f}, x1 = {0.f, 0.f, 0.f, 0.f};
        int4 a = {0, 0, 0, 0}; float4 d = {0.f, 0.f, 0.f, 0.f};
        if (u + 1 < 16) {
            const float* sb = xlbase + (size_t)((u + 1) * 32) * OD;
            x0 = *(const float4*)(sb + (size_t)fr0 * OD + fs);
            x1 = *(const float4*)(sb + (size_t)(fr0 + 16) * OD + fs);
            if (t < 32) {
                a = *(const int4*)(ajbase + (size_t)((u + 1) * 32 + t) * N_);
                d = *(const float4*)(dlbase + ((u + 1) * 32 + t) * H_);
            }
        }

        // ---- compute u from buf[cur] ----
        float p[8];
        #pragma unroll
        for (int e = 0; e < 8; ++e) p[e] = xls[cur][js][cbase + e];
        int4  wm = adjs[cur][js];
        float wd = dls[cur][js][h];
        const int j = u * 32 + js;
        v2f p0 = (v2f){p[0], p[1]}, p1 = (v2f){p[2], p[3]};
        v2f p2 = (v2f){p[4], p[5]}, p3 = (v2f){p[6], p[7]};
        int wmv[TI] = {wm.x, wm.y, wm.z, wm.w};
        #pragma unroll
        for (int il = 0; il < TI; ++il) {
            v2f s01 = pk_add(xrv[il][0], p0);
            v2f s23 = pk_add(xrv[il][1], p1);
            v2f s45 = pk_add(xrv[il][2], p2);
            v2f s67 = pk_add(xrv[il][3], p3);
            float e2a = 0.f, e2b = 0.f;
            e2a = fmaf(atS[0], __builtin_fabsf(s01.x), e2a);
            e2b = fmaf(atS[1], __builtin_fabsf(s01.y), e2b);
            e2a = fmaf(atS[2], __builtin_fabsf(s23.x), e2a);
            e2b = fmaf(atS[3], __builtin_fabsf(s23.y), e2b);
            e2a = fmaf(atS[4], __builtin_fabsf(s45.x), e2a);
            e2b = fmaf(atS[5], __builtin_fabsf(s45.y), e2b);
            e2a = fmaf(atS[6], __builtin_fabsf(s67.x), e2a);
            e2b = fmaf(atS[7], __builtin_fabsf(s67.y), e2b);
            float eh = e2a + e2b;
            eh = dpp_add<0xB1>(eh);          // + lane^1 (quad_perm 1,0,3,2)
            eh = dpp_add<0x4E>(eh);          // + lane^2 (quad_perm 2,3,0,1)
            float e = wd + eh;               // log2 logit (drv cancels in softmax)
            bool keep = (wmv[il] != 0) || (j == i0 + il);
            float w = keep ? fast_exp2(e) : 0.f;
            sumw[il] += w;
            v2f ws = (v2f){w, w};
            pk_fma(acc[il][0], ws, p0);
            pk_fma(acc[il][1], ws, p1);
            pk_fma(acc[il][2], ws, p2);
            pk_fma(acc[il][3], ws, p3);
        }

        // ---- write-late: strip u+1 into buf[nxt] (readers of nxt passed
        //      the previous barrier; one barrier per u suffices) ----
        if (u + 1 < 16) {
            float* w0 = &xls[nxt][fr0][fs];
            w0[0] = x0.x; w0[1] = x0.y; w0[2] = x0.z; w0[3] = x0.w;
            float* w1 = &xls[nxt][fr0 + 16][fs];
            w1[0] = x1.x; w1[1] = x1.y; w1[2] = x1.z; w1[3] = x1.w;
            if (t < 32) { adjs[nxt][t] = a; *(float4*)dls[nxt][t] = d; }
        }
        __syncthreads();
    }

    // ---- epilogue: two il-passes; LDS reused (main loop fully barriered) ----
    float (*sacc)[2][32][PH + 1] = (float (*)[2][32][PH + 1])(lds_raw); // 33792B
    float (*ssum)[32][TI]        = (float (*)[32][TI])(lds_raw + 33792); // 2048B

    if (cq == 0) {
        #pragma unroll
        for (int il = 0; il < TI; ++il)
            ssum[h][js][il] = sumw[il];
    }
    // pass 0: il 0,1   (write banks (js+8cq)%32: exactly 2-way, free)
    #pragma unroll
    for (int p = 0; p < 2; ++p) {
        *(float4*)(&sacc[h][p][js][cq * 8]) =
            make_float4(acc[p][0].x, acc[p][0].y, acc[p][1].x, acc[p][1].y);
        *(float4*)(&sacc[h][p][js][cq * 8 + 4]) =
            make_float4(acc[p][2].x, acc[p][2].y, acc[p][3].x, acc[p][3].y);
    }
    __syncthreads();
    if (t < 256) {
        const int c   = t & 31;
        const int ilr = (t >> 5) & 1;
        const int hr  = t >> 6;
        float av = 0.f, st = 0.f;
        #pragma unroll
        for (int k = 0; k < 32; ++k) {
            av += sacc[hr][ilr][k][c];       // banks (k+c)%32: conflict-free
            st += ssum[hr][k][ilr];
        }
        const int cg = hr * PH + c;
        out[((size_t)(b * N_ + i0 + ilr)) * OD + cg] =
            fmaf(av, 1.f / st, bias[cg]);
    }
    __syncthreads();
    // pass 1: il 2,3
    #pragma unroll
    for (int p = 0; p < 2; ++p) {
        *(float4*)(&sacc[h][p][js][cq * 8]) =
            make_float4(acc[2 + p][0].x, acc[2 + p][0].y,
                        acc[2 + p][1].x, acc[2 + p][1].y);
        *(float4*)(&sacc[h][p][js][cq * 8 + 4]) =
            make_float4(acc[2 + p][2].x, acc[2 + p][2].y,
                        acc[2 + p][3].x, acc[2 + p][3].y);
    }
    __syncthreads();
    if (t < 256) {
        const int c   = t & 31;
        const int ilr = (t >> 5) & 1;
        const int hr  = t >> 6;
        float av = 0.f, st = 0.f;
        #pragma unroll
        for (int k = 0; k < 32; ++k) {
            av += sacc[hr][ilr][k][c];
            st += ssum[hr][k][2 + ilr];
        }
        const int cg = hr * PH + c;
        out[((size_t)(b * N_ + i0 + 2 + ilr)) * OD + cg] =
            fmaf(av, 1.f / st, bias[cg]);
    }
}

extern "C" void kernel_launch(void* const* d_in, const int* in_sizes, int n_in,
                              void* d_out, int out_size, void* d_ws, size_t ws_size,
                              hipStream_t stream) {
    const float* x    = (const float*)d_in[0];
    const int*   adj  = (const int*)d_in[1];
    const float* Wl   = (const float*)d_in[2];
    const float* bl   = (const float*)d_in[3];
    const float* Wr   = (const float*)d_in[4];
    const float* br   = (const float*)d_in[5];
    const float* att  = (const float*)d_in[6];
    const float* bias = (const float*)d_in[7];
    float* out = (float*)d_out;

    float* xl = (float*)d_ws;                    // 2 MB
    float* xr = xl + (size_t)B_ * N_ * OD;       // 2 MB
    float* dl = xr + (size_t)B_ * N_ * OD;       // 64 KB
    float* dr = dl + (size_t)B_ * N_ * H_;       // 64 KB

    proj_kernel<<<512, 512, 0, stream>>>(x, Wl, bl, Wr, br, att, xl, xr, dl, dr);
    attn_kernel<<<1024, 512, 0, stream>>>(adj, att, bias, xl, xr, dl, dr, out);
}

// Round 13
// 119.066 us; speedup vs baseline: 1.2685x; 1.2685x over previous
//
#include <hip/hip_runtime.h>

#define B_   8
#define N_   512
#define IND  256
#define H_   4
#define PH   32
#define OD   128   // H_*PH
#define TI   4     // targets per block (attn)

typedef float v2f __attribute__((ext_vector_type(2)));

// leaky 0.4 * log2(e), and 0.6 * log2(e): logits in log2 domain -> v_exp_f32.
#define ATT_SCALE 0.5770780163555854f
#define DLR_SCALE 0.8656170245333781f

template <int PAT>
__device__ __forceinline__ float dpp_add(float x) {
    int yi = __builtin_amdgcn_mov_dpp(__float_as_int(x), PAT, 0xF, 0xF, true);
    return x + __int_as_float(yi);
}

__device__ __forceinline__ float fast_exp2(float x) {
#if __has_builtin(__builtin_amdgcn_exp2f)
    return __builtin_amdgcn_exp2f(x);
#else
    return exp2f(x);
#endif
}

// Packed fp32 FMA: d += a*b on both halves, ONE VOP3P instruction.
__device__ __forceinline__ void pk_fma(v2f& d, v2f a, v2f b) {
    asm("v_pk_fma_f32 %0, %1, %2, %0" : "+v"(d) : "v"(a), "v"(b));
}

// ---------------------------------------------------------------------------
// SESSION SUMMARY (13 rounds): best total = 120.97us with THIS exact pair
// (round 6; round-12 resubmit failed on container acquisition, not kernel).
// Budget: harness ws-poison fill 42us (268MB @ 6.4TB/s, in-window,
// kernel-side unavoidable) + attn 41us + proj ~33us + gaps.
//   attn 41us: resistant to -14% VALU (pk_add r7), -10% mask-fold (r9),
//     2x TLP (r6), LDS staging (r11: 6.3M bank conflicts + spill, -36us).
//   proj ~33us: cold-miss latency in the fill's writeback shadow. PROVEN
//     kernel-invariant by the r10 2x-rep diagnostic (2nd rep ~3us) across
//     6 structures (2-32 waves/CU, 1-4x W redundancy, 1/2/4-deep prefetch,
//     +-45% VALU). Warm floor ~3us; cold shadow is environmental.
// Failed levers (counters in journal): launch_bounds cap = 256/min_waves
// (VGPR spill at (256,4)/(256,6)/(512,6)); fp32 VOP3P is 2-pass (no issue
// win); emask precompute (+16MB traffic, null); LDS operand staging (write
// banks (fr0+4t)%32 = 8-way).
// ---------------------------------------------------------------------------

// ---------------------------------------------------------------------------
// Kernel 1 v7 (round-6 exact): xl = x@Wl + bl ; xr = x@Wr + br  plus the
// pre-scaled rank-1 parts dl/dr. 4 rows/block, 256 thr = og32 x ks4 x which2,
// grid 1024 -> 4 blocks/CU; W read exactly once per block; thread = 4 rows x
// 4 cols x 64k, chunk 2k, 1-deep parity W prefetch; 4-way K-split combined
// through stride-17 LDS (<=2-way banks); coalesced float4 outputs.
// ---------------------------------------------------------------------------
__global__ __launch_bounds__(256, 4) void proj_kernel(
    const float* __restrict__ x,
    const float* __restrict__ Wl, const float* __restrict__ bl,
    const float* __restrict__ Wr, const float* __restrict__ br,
    const float* __restrict__ att,
    float* __restrict__ xl, float* __restrict__ xr,
    float* __restrict__ dl, float* __restrict__ dr)
{
    __shared__ float xs[4 * IND];        // 4 KB
    __shared__ float comb[4][64][17];    // 17408 B

    const int t = threadIdx.x;
    const int row0 = blockIdx.x * 4;

    ((float4*)xs)[t] = ((const float4*)(x + (size_t)row0 * IND))[t];
    __syncthreads();

    const int og    = t & 31;        // col quad: cols og*4 .. og*4+3
    const int ks    = (t >> 5) & 3;  // K slice: k0 = ks*64
    const int which = t >> 7;        // 0: Wl->xl/dl, 1: Wr->xr/dr
    const int o0 = og * 4;
    const int k0 = ks * 64;
    const float* W = (which ? Wr : Wl) + (size_t)k0 * OD + o0;

    float acc[4][4];
    #pragma unroll
    for (int r = 0; r < 4; ++r)
        #pragma unroll
        for (int c = 0; c < 4; ++c) acc[r][c] = 0.f;

    float4 wb[2][2];
    wb[0][0] = *(const float4*)(W);
    wb[0][1] = *(const float4*)(W + OD);

    #pragma unroll 2
    for (int s = 0; s < 32; ++s) {       // 32 chunks of 2 k (K=64 per thread)
        const int cur = s & 1, nxt = cur ^ 1;
        if (s < 31) {
            const float* Wq = W + (size_t)(2 * (s + 1)) * OD;
            wb[nxt][0] = *(const float4*)(Wq);
            wb[nxt][1] = *(const float4*)(Wq + OD);
        }
        #pragma unroll
        for (int r = 0; r < 4; ++r) {
            float2 xv = *(const float2*)(&xs[r * IND + k0 + 2 * s]);
            acc[r][0] = fmaf(xv.x, wb[cur][0].x, acc[r][0]);
            acc[r][1] = fmaf(xv.x, wb[cur][0].y, acc[r][1]);
            acc[r][2] = fmaf(xv.x, wb[cur][0].z, acc[r][2]);
            acc[r][3] = fmaf(xv.x, wb[cur][0].w, acc[r][3]);
            acc[r][0] = fmaf(xv.y, wb[cur][1].x, acc[r][0]);
            acc[r][1] = fmaf(xv.y, wb[cur][1].y, acc[r][1]);
            acc[r][2] = fmaf(xv.y, wb[cur][1].z, acc[r][2]);
            acc[r][3] = fmaf(xv.y, wb[cur][1].w, acc[r][3]);
        }
    }

    // stage ALL 4 K-slice partials (banks (17*og+i)%32: og-bijective, 2-way)
    const int pid = og | (which << 5);   // 0..63
    #pragma unroll
    for (int i = 0; i < 16; ++i)
        comb[ks][pid][i] = acc[i >> 2][i & 3];
    __syncthreads();

    // final: remap thread -> (og', row', which'); one float4 output each
    const int ogf = t & 31;
    const int rf  = (t >> 5) & 3;
    const int whf = t >> 7;
    const int pidf = ogf | (whf << 5);
    const float* bb = whf ? br : bl;
    float* dst = whf ? xr : xl;
    float* dp  = whf ? dr : dl;
    float4 bv = *(const float4*)(bb + ogf * 4);
    float4 av = *(const float4*)(att + ogf * 4);
    const float bvf[4] = {bv.x, bv.y, bv.z, bv.w};
    const float avf[4] = {av.x, av.y, av.z, av.w};
    float y[4];
    #pragma unroll
    for (int c = 0; c < 4; ++c) {
        const int idx = rf * 4 + c;
        y[c] = ((comb[0][pidf][idx] + comb[1][pidf][idx])
              + (comb[2][pidf][idx] + comb[3][pidf][idx])) + bvf[c];
    }
    *(float4*)(&dst[(size_t)(row0 + rf) * OD + ogf * 4]) =
        make_float4(y[0], y[1], y[2], y[3]);
    // rank-1 part: dl/dr[n,h] = 0.6*log2e * sum_c att[h,c]*y[c]
    float dc = fmaf(avf[0], y[0], fmaf(avf[1], y[1],
               fmaf(avf[2], y[2], avf[3] * y[3])));
    dc += __shfl_xor(dc, 1);
    dc += __shfl_xor(dc, 2);
    dc += __shfl_xor(dc, 4);   // sums the 8 og-lanes of one head
    if ((ogf & 7) == 0)
        dp[(size_t)(row0 + rf) * H_ + (ogf >> 3)] = DLR_SCALE * dc;
}

// ---------------------------------------------------------------------------
// Kernel 2 v7 (round-6 exact, best measured: 40.9us, no spill): 512-thread
// blocks, js = 32 j-slices, u-loop 16 -> 4 blocks/CU x 8 waves = 32 waves/CU.
// drv dropped (cancels exactly between softmax numerator and denominator).
// TI=4, manual 1-deep pipeline, XCD<->batch swizzle (FETCH 42->6 MB),
// 2-pass conflict-free LDS epilogue.
// ---------------------------------------------------------------------------
__global__ __launch_bounds__(512, 4) void attn_kernel(
    const int* __restrict__ adj, const float* __restrict__ att,
    const float* __restrict__ bias,
    const float* __restrict__ xl, const float* __restrict__ xr,
    const float* __restrict__ dl, const float* __restrict__ dr,
    float* __restrict__ out)
{
    __shared__ float sacc[H_][2][32][PH + 1];  // 33792 B (two il per pass)
    __shared__ float ssum[H_][32][TI];         // 2 KB

    const int t = threadIdx.x;
    const int bid = (blockIdx.x & 7) * 128 + (blockIdx.x >> 3);
    const int b  = bid >> 7;
    const int i0 = (bid & 127) * TI;
    const int cq = t & 3;
    const int js = (t >> 2) & 31;   // 32 j-slices
    const int h  = t >> 7;
    const int cbase = h * PH + cq * 8;

    // preload att (pre-scaled by 0.4*log2e) and xr fragments for all 4 targets
    float atS[8];
    {
        const float* ap = att + cbase;
        float4 a0 = *(const float4*)(ap);
        float4 a1 = *(const float4*)(ap + 4);
        atS[0] = ATT_SCALE * a0.x; atS[1] = ATT_SCALE * a0.y;
        atS[2] = ATT_SCALE * a0.z; atS[3] = ATT_SCALE * a0.w;
        atS[4] = ATT_SCALE * a1.x; atS[5] = ATT_SCALE * a1.y;
        atS[6] = ATT_SCALE * a1.z; atS[7] = ATT_SCALE * a1.w;
    }
    float xrS[TI][8];
    #pragma unroll
    for (int il = 0; il < TI; ++il) {
        const float* xp = xr + ((size_t)(b * N_ + i0 + il)) * OD + cbase;
        float4 r0 = *(const float4*)(xp);
        float4 r1 = *(const float4*)(xp + 4);
        xrS[il][0] = r0.x; xrS[il][1] = r0.y; xrS[il][2] = r0.z; xrS[il][3] = r0.w;
        xrS[il][4] = r1.x; xrS[il][5] = r1.y; xrS[il][6] = r1.z; xrS[il][7] = r1.w;
    }

    v2f acc[TI][4];
    float sumw[TI];
    #pragma unroll
    for (int il = 0; il < TI; ++il) {
        sumw[il] = 0.f;
        #pragma unroll
        for (int m = 0; m < 4; ++m) acc[il][m] = (v2f){0.f, 0.f};
    }

    // software-pipelined j-loop: j = u*32 + js, u = 0..15
    const float* xlp = xl + ((size_t)(b * N_ + js)) * OD + cbase;
    const int*   ajp = adj + ((size_t)(b * N_ + js)) * N_ + i0;
    const float* dlp = dl + ((size_t)(b * N_ + js)) * H_ + h;

    float4 va = *(const float4*)(xlp);
    float4 vb = *(const float4*)(xlp + 4);
    int4   mj = *(const int4*)(ajp);
    float  dj = *dlp;

    #pragma unroll 2
    for (int u = 0; u < 16; ++u) {
        float4 wa = va, wb = vb;
        int4   wm = mj;
        float  wd = dj;
        if (u < 15) {
            xlp += 32 * OD; ajp += 32 * N_; dlp += 32 * H_;
            va = *(const float4*)(xlp);
            vb = *(const float4*)(xlp + 4);
            mj = *(const int4*)(ajp);
            dj = *dlp;
        }
        const int j = u * 32 + js;
        v2f p0 = (v2f){wa.x, wa.y}, p1 = (v2f){wa.z, wa.w};
        v2f p2 = (v2f){wb.x, wb.y}, p3 = (v2f){wb.z, wb.w};
        int wmv[TI] = {wm.x, wm.y, wm.z, wm.w};
        #pragma unroll
        for (int il = 0; il < TI; ++il) {
            float s, e2a = 0.f, e2b = 0.f;
            s = xrS[il][0] + wa.x; e2a = fmaf(atS[0], __builtin_fabsf(s), e2a);
            s = xrS[il][1] + wa.y; e2b = fmaf(atS[1], __builtin_fabsf(s), e2b);
            s = xrS[il][2] + wa.z; e2a = fmaf(atS[2], __builtin_fabsf(s), e2a);
            s = xrS[il][3] + wa.w; e2b = fmaf(atS[3], __builtin_fabsf(s), e2b);
            s = xrS[il][4] + wb.x; e2a = fmaf(atS[4], __builtin_fabsf(s), e2a);
            s = xrS[il][5] + wb.y; e2b = fmaf(atS[5], __builtin_fabsf(s), e2b);
            s = xrS[il][6] + wb.z; e2a = fmaf(atS[6], __builtin_fabsf(s), e2a);
            s = xrS[il][7] + wb.w; e2b = fmaf(atS[7], __builtin_fabsf(s), e2b);
            float eh = e2a + e2b;
            eh = dpp_add<0xB1>(eh);          // + lane^1 (quad_perm 1,0,3,2)
            eh = dpp_add<0x4E>(eh);          // + lane^2 (quad_perm 2,3,0,1)
            float e = wd + eh;               // log2 logit (drv cancels in softmax)
            bool keep = (wmv[il] != 0) || (j == i0 + il);
            float w = keep ? fast_exp2(e) : 0.f;
            sumw[il] += w;
            v2f ws = (v2f){w, w};
            pk_fma(acc[il][0], ws, p0);
            pk_fma(acc[il][1], ws, p1);
            pk_fma(acc[il][2], ws, p2);
            pk_fma(acc[il][3], ws, p3);
        }
    }

    // ---- epilogue: two il-passes through LDS; reduce over the 32 js ----
    if (cq == 0) {
        #pragma unroll
        for (int il = 0; il < TI; ++il)
            ssum[h][js][il] = sumw[il];
    }
    // pass 0: il 0,1   (write banks (js+8cq)%32: exactly 2-way, free)
    #pragma unroll
    for (int p = 0; p < 2; ++p) {
        *(float4*)(&sacc[h][p][js][cq * 8]) =
            make_float4(acc[p][0].x, acc[p][0].y, acc[p][1].x, acc[p][1].y);
        *(float4*)(&sacc[h][p][js][cq * 8 + 4]) =
            make_float4(acc[p][2].x, acc[p][2].y, acc[p][3].x, acc[p][3].y);
    }
    __syncthreads();
    if (t < 256) {
        const int c   = t & 31;
        const int ilr = (t >> 5) & 1;
        const int hr  = t >> 6;
        float a = 0.f, st = 0.f;
        #pragma unroll
        for (int k = 0; k < 32; ++k) {
            a  += sacc[hr][ilr][k][c];       // banks (k+c)%32: conflict-free
            st += ssum[hr][k][ilr];
        }
        const int cg = hr * PH + c;
        out[((size_t)(b * N_ + i0 + ilr)) * OD + cg] =
            fmaf(a, 1.f / st, bias[cg]);
    }
    __syncthreads();
    // pass 1: il 2,3
    #pragma unroll
    for (int p = 0; p < 2; ++p) {
        *(float4*)(&sacc[h][p][js][cq * 8]) =
            make_float4(acc[2 + p][0].x, acc[2 + p][0].y,
                        acc[2 + p][1].x, acc[2 + p][1].y);
        *(float4*)(&sacc[h][p][js][cq * 8 + 4]) =
            make_float4(acc[2 + p][2].x, acc[2 + p][2].y,
                        acc[2 + p][3].x, acc[2 + p][3].y);
    }
    __syncthreads();
    if (t < 256) {
        const int c   = t & 31;
        const int ilr = (t >> 5) & 1;
        const int hr  = t >> 6;
        float a = 0.f, st = 0.f;
        #pragma unroll
        for (int k = 0; k < 32; ++k) {
            a  += sacc[hr][ilr][k][c];
            st += ssum[hr][k][2 + ilr];
        }
        const int cg = hr * PH + c;
        out[((size_t)(b * N_ + i0 + 2 + ilr)) * OD + cg] =
            fmaf(a, 1.f / st, bias[cg]);
    }
}

extern "C" void kernel_launch(void* const* d_in, const int* in_sizes, int n_in,
                              void* d_out, int out_size, void* d_ws, size_t ws_size,
                              hipStream_t stream) {
    const float* x    = (const float*)d_in[0];
    const int*   adj  = (const int*)d_in[1];
    const float* Wl   = (const float*)d_in[2];
    const float* bl   = (const float*)d_in[3];
    const float* Wr   = (const float*)d_in[4];
    const float* br   = (const float*)d_in[5];
    const float* att  = (const float*)d_in[6];
    const float* bias = (const float*)d_in[7];
    float* out = (float*)d_out;

    float* xl = (float*)d_ws;                    // 2 MB
    float* xr = xl + (size_t)B_ * N_ * OD;       // 2 MB
    float* dl = xr + (size_t)B_ * N_ * OD;       // 64 KB
    float* dr = dl + (size_t)B_ * N_ * H_;       // 64 KB

    proj_kernel<<<1024, 256, 0, stream>>>(x, Wl, bl, Wr, br, att, xl, xr, dl, dr);
    attn_kernel<<<1024, 512, 0, stream>>>(adj, att, bias, xl, xr, dl, dr, out);
}